// Round 1
// 777.976 us; speedup vs baseline: 4.3883x; 4.3883x over previous
//
#include <hip/hip_runtime.h>
#include <stdint.h>

// SDPA fp32 via MFMA with bf16x3 compensation. B=2 H=16 L=2048 D=64.
// Block = 64 q-rows of one (b,h), 4 waves x 16 rows.
// Pass A: plain-bf16 QK^T, rowsum of exp (no storage).  error on 1/sum ~1.4e-4 rel.
// Pass B: bf16x3 QK^T (Ah*Bh + Al*Bh + Ah*Bl, residual ~2^-17) -> p = exp(s/8)*inv,
//         p round-trips per-wave LDS scratch for coalesced attn stores + PV A-frags,
//         PV bf16x3 with V transposed into swizzled LDS.
// LDS: 16KB hi/lo staging (K then V) + 4x16x68 f32 p-scratch = 33.8KB -> multi-block/CU.

#define L_SEQ 2048
#define D_HEAD 64
#define N_BH   32
#define BQ     64
#define BK     64
#define NT     256

typedef float f32x4 __attribute__((ext_vector_type(4)));
typedef short s16x8 __attribute__((ext_vector_type(8)));

#define MFMA16(A, B, C) __builtin_amdgcn_mfma_f32_16x16x32_bf16((A), (B), (C), 0, 0, 0)

__device__ __forceinline__ unsigned int bf16_rne_u(float x) {
    union { float f; unsigned int u; } c; c.f = x;
    return (c.u + 0x7FFFu + ((c.u >> 16) & 1u)) >> 16;
}
__device__ __forceinline__ float bf16_f32(unsigned int h) {
    union { unsigned int u; float f; } c; c.u = h << 16;
    return c.f;
}

__global__ __launch_bounds__(NT, 2)
void sdpa_mfma_kernel(const float* __restrict__ qg,
                      const float* __restrict__ kg,
                      const float* __restrict__ vg,
                      float* __restrict__ ctx,
                      float* __restrict__ attn)
{
    extern __shared__ char lds[];
    char*  SH = lds;                        // hi plane: [64 rows][64 bf16] swizzled, 8KB
    char*  SL = lds + 8192;                 // lo plane, 8KB
    float* PS = (float*)(lds + 16384);      // per-wave p scratch: [4][16][68] f32

    const int t    = threadIdx.x;
    const int lane = t & 63;
    const int wid  = t >> 6;
    const int c    = lane & 15;             // col lane within 16-wide frag
    const int g    = lane >> 4;             // k-group 0..3

    const int bh = blockIdx.y;
    const int q0 = blockIdx.x * BQ;

    const float* qb = qg + (size_t)bh * L_SEQ * D_HEAD;
    const float* kb = kg + (size_t)bh * L_SEQ * D_HEAD;
    const float* vb = vg + (size_t)bh * L_SEQ * D_HEAD;

    float* PSw = PS + wid * (16 * 68);

    // ---- Q A-fragments (hi/lo): row = lane&15 (of this wave's 16 rows), k = kf*32 + g*8 + i
    s16x8 qhi[2], qlo[2];
    {
        const float* qr = qb + (size_t)(q0 + wid * 16 + c) * D_HEAD + g * 8;
        #pragma unroll
        for (int kf = 0; kf < 2; ++kf) {
            float4 a = *(const float4*)(qr + kf * 32);
            float4 b = *(const float4*)(qr + kf * 32 + 4);
            float v[8] = {a.x, a.y, a.z, a.w, b.x, b.y, b.z, b.w};
            #pragma unroll
            for (int i = 0; i < 8; ++i) {
                unsigned int h = bf16_rne_u(v[i]);
                qhi[kf][i] = (short)h;
                qlo[kf][i] = (short)bf16_rne_u(v[i] - bf16_f32(h));
            }
        }
    }

    // ======== Pass A: rowsums of exp(QK^T/8), plain bf16 ========
    float rs[4] = {0.f, 0.f, 0.f, 0.f};

    #pragma unroll 1
    for (int kt = 0; kt < L_SEQ / BK; ++kt) {
        __syncthreads();
        {   // stage K tile, hi only: row j, 64 bf16 (128B) per row, XOR-swizzled
            const float* kt0 = kb + (size_t)kt * BK * D_HEAD;
            #pragma unroll
            for (int ii = 0; ii < 4; ++ii) {
                int idx = ii * NT + t;
                int r = idx >> 4, c4 = idx & 15;
                float4 val = ((const float4*)(kt0 + (size_t)r * D_HEAD))[c4];
                ushort4 h;
                h.x = (unsigned short)bf16_rne_u(val.x);
                h.y = (unsigned short)bf16_rne_u(val.y);
                h.z = (unsigned short)bf16_rne_u(val.z);
                h.w = (unsigned short)bf16_rne_u(val.w);
                *(ushort4*)(SH + r * 128 + ((c4 * 8) ^ ((r & 7) << 4))) = h;
            }
        }
        __syncthreads();
        #pragma unroll
        for (int cg = 0; cg < 4; ++cg) {
            int j = cg * 16 + c;
            int key = (j & 7) << 4;
            const char* rh = SH + j * 128;
            s16x8 b0 = *(const s16x8*)(rh + ((g * 16) ^ key));
            s16x8 b1 = *(const s16x8*)(rh + ((64 + g * 16) ^ key));
            f32x4 s = {0.f, 0.f, 0.f, 0.f};
            s = MFMA16(qhi[0], b0, s);
            s = MFMA16(qhi[1], b1, s);
            #pragma unroll
            for (int r = 0; r < 4; ++r) rs[r] += __expf(s[r] * 0.125f);
        }
    }

    float inv[4];
    #pragma unroll
    for (int r = 0; r < 4; ++r) {
        float s = rs[r];
        s += __shfl_xor(s, 1); s += __shfl_xor(s, 2);
        s += __shfl_xor(s, 4); s += __shfl_xor(s, 8);
        inv[r] = 1.0f / s;
    }

    // ======== Pass B: bf16x3 S -> p -> attn store + PV ========
    float* ab = attn + (size_t)(bh * L_SEQ + q0 + wid * 16) * L_SEQ;
    f32x4 cacc[4];
    #pragma unroll
    for (int cg = 0; cg < 4; ++cg) cacc[cg] = (f32x4){0.f, 0.f, 0.f, 0.f};

    #pragma unroll 1
    for (int kt = 0; kt < L_SEQ / BK; ++kt) {
        __syncthreads();                                       // B1
        {   // stage K tile hi+lo
            const float* kt0 = kb + (size_t)kt * BK * D_HEAD;
            #pragma unroll
            for (int ii = 0; ii < 4; ++ii) {
                int idx = ii * NT + t;
                int r = idx >> 4, c4 = idx & 15;
                float4 val = ((const float4*)(kt0 + (size_t)r * D_HEAD))[c4];
                ushort4 h, l;
                unsigned int hx = bf16_rne_u(val.x), hy = bf16_rne_u(val.y);
                unsigned int hz = bf16_rne_u(val.z), hw = bf16_rne_u(val.w);
                h.x = (unsigned short)hx; h.y = (unsigned short)hy;
                h.z = (unsigned short)hz; h.w = (unsigned short)hw;
                l.x = (unsigned short)bf16_rne_u(val.x - bf16_f32(hx));
                l.y = (unsigned short)bf16_rne_u(val.y - bf16_f32(hy));
                l.z = (unsigned short)bf16_rne_u(val.z - bf16_f32(hz));
                l.w = (unsigned short)bf16_rne_u(val.w - bf16_f32(hw));
                int off = r * 128 + ((c4 * 8) ^ ((r & 7) << 4));
                *(ushort4*)(SH + off) = h;
                *(ushort4*)(SL + off) = l;
            }
        }
        __syncthreads();                                       // B2
        // S = QK^T bf16x3; p = exp(s/8)*inv -> per-wave LDS scratch
        #pragma unroll
        for (int cg = 0; cg < 4; ++cg) {
            int j = cg * 16 + c;
            int key = (j & 7) << 4;
            const char* rh = SH + j * 128;
            const char* rl = SL + j * 128;
            s16x8 bh0 = *(const s16x8*)(rh + ((g * 16) ^ key));
            s16x8 bh1 = *(const s16x8*)(rh + ((64 + g * 16) ^ key));
            s16x8 bl0 = *(const s16x8*)(rl + ((g * 16) ^ key));
            s16x8 bl1 = *(const s16x8*)(rl + ((64 + g * 16) ^ key));
            f32x4 s = {0.f, 0.f, 0.f, 0.f};
            s = MFMA16(qhi[0], bh0, s);
            s = MFMA16(qhi[1], bh1, s);
            s = MFMA16(qlo[0], bh0, s);
            s = MFMA16(qlo[1], bh1, s);
            s = MFMA16(qhi[0], bl0, s);
            s = MFMA16(qhi[1], bl1, s);
            #pragma unroll
            for (int r = 0; r < 4; ++r) {
                float p = __expf(s[r] * 0.125f) * inv[r];
                PSw[(g * 4 + r) * 68 + cg * 16 + c] = p;       // row g*4+r, col cg*16+c
            }
        }
        __syncthreads();                                       // B3 (PS writes drained)
        {   // stage V transposed hi+lo: Vt[d][j], bf16, swizzled
            const float* vt0 = vb + (size_t)kt * BK * D_HEAD;
            #pragma unroll
            for (int ii = 0; ii < 2; ++ii) {
                int item = ii * NT + t;
                int d4 = item & 15, j2 = item >> 4;            // j2: 0..31
                const float* r0 = vt0 + (size_t)(2 * j2) * D_HEAD + d4 * 4;
                float4 a = *(const float4*)r0;
                float4 b = *(const float4*)(r0 + D_HEAD);
                float av[4] = {a.x, a.y, a.z, a.w};
                float bv[4] = {b.x, b.y, b.z, b.w};
                #pragma unroll
                for (int i = 0; i < 4; ++i) {
                    int d = d4 * 4 + i;
                    unsigned int h0 = bf16_rne_u(av[i]);
                    unsigned int h1 = bf16_rne_u(bv[i]);
                    unsigned int l0 = bf16_rne_u(av[i] - bf16_f32(h0));
                    unsigned int l1 = bf16_rne_u(bv[i] - bf16_f32(h1));
                    int off = d * 128 + ((4 * j2) ^ ((d & 7) << 4));
                    *(unsigned int*)(SH + off) = h0 | (h1 << 16);
                    *(unsigned int*)(SL + off) = l0 | (l1 << 16);
                }
            }
        }
        __syncthreads();                                       // B4
        // attn store: coalesced 256B per row from PS
        #pragma unroll
        for (int it = 0; it < 4; ++it) {
            int r2 = it * 4 + g;
            float4 pv = *(const float4*)(PSw + r2 * 68 + c * 4);
            *(float4*)(ab + (size_t)r2 * L_SEQ + kt * BK + c * 4) = pv;
        }
        // P A-frags (hi/lo): row = lane&15, k(j) = kf*32 + g*8 + i
        s16x8 ph[2], pl[2];
        {
            const float* pr = PSw + c * 68;
            #pragma unroll
            for (int kf = 0; kf < 2; ++kf) {
                float4 a = *(const float4*)(pr + kf * 32 + g * 8);
                float4 b = *(const float4*)(pr + kf * 32 + g * 8 + 4);
                float v[8] = {a.x, a.y, a.z, a.w, b.x, b.y, b.z, b.w};
                #pragma unroll
                for (int i = 0; i < 8; ++i) {
                    unsigned int h = bf16_rne_u(v[i]);
                    ph[kf][i] = (short)h;
                    pl[kf][i] = (short)bf16_rne_u(v[i] - bf16_f32(h));
                }
            }
        }
        // PV bf16x3
        #pragma unroll
        for (int cg = 0; cg < 4; ++cg) {
            int d = cg * 16 + c;
            int key = (d & 7) << 4;
            const char* rh = SH + d * 128;
            const char* rl = SL + d * 128;
            s16x8 vh0 = *(const s16x8*)(rh + ((g * 16) ^ key));
            s16x8 vh1 = *(const s16x8*)(rh + ((64 + g * 16) ^ key));
            s16x8 vl0 = *(const s16x8*)(rl + ((g * 16) ^ key));
            s16x8 vl1 = *(const s16x8*)(rl + ((64 + g * 16) ^ key));
            f32x4 cc = cacc[cg];
            cc = MFMA16(ph[0], vh0, cc);
            cc = MFMA16(ph[1], vh1, cc);
            cc = MFMA16(pl[0], vh0, cc);
            cc = MFMA16(pl[1], vh1, cc);
            cc = MFMA16(ph[0], vl0, cc);
            cc = MFMA16(ph[1], vl1, cc);
            cacc[cg] = cc;
        }
    }

    // ---- context store: C[row = g*4+r][d = cg*16+c]
    float* cb = ctx + (size_t)(bh * L_SEQ + q0 + wid * 16) * D_HEAD;
    #pragma unroll
    for (int cg = 0; cg < 4; ++cg) {
        #pragma unroll
        for (int r = 0; r < 4; ++r) {
            cb[(size_t)(g * 4 + r) * D_HEAD + cg * 16 + c] = cacc[cg][r];
        }
    }
}

extern "C" void kernel_launch(void* const* d_in, const int* in_sizes, int n_in,
                              void* d_out, int out_size, void* d_ws, size_t ws_size,
                              hipStream_t stream) {
    const float* q = (const float*)d_in[0];
    const float* k = (const float*)d_in[1];
    const float* v = (const float*)d_in[2];
    float* ctx  = (float*)d_out;
    float* attn = ctx + (size_t)N_BH * L_SEQ * D_HEAD;  // context first, then attention

    dim3 grid(L_SEQ / BQ, N_BH);     // 32 x 32 = 1024 blocks
    size_t smem = 16384 + (size_t)4 * 16 * 68 * sizeof(float);  // 33792 B
    hipLaunchKernelGGL(sdpa_mfma_kernel, grid, dim3(NT), smem, stream,
                       q, k, v, ctx, attn);
}

// Round 2
// 696.981 us; speedup vs baseline: 4.8982x; 1.1162x over previous
//
#include <hip/hip_runtime.h>
#include <stdint.h>

// SDPA fp32 via MFMA, bf16x3 compensated. B=2 H=16 L=2048 D=64.
// R2: pre-pass converts Q,K -> bf16 hi/lo planes and V -> TRANSPOSED bf16 hi/lo
// planes in d_ws (50.3 MB). Main kernel staging is pure copy (no VALU convert),
// K and V in separate LDS buffers -> 2 barriers/kt, T14 prefetch (load next tile
// into regs during compute). Per-wave LDS scratch for P redistribution (no barrier).
// XCD-bijective block swizzle: each XCD owns 4 bh -> K/V working set ~4MB = L2-resident.

#define L_SEQ 2048
#define D_HEAD 64
#define N_BH   32
#define BQ     64
#define BK     64
#define NT     256
#define NKT    (L_SEQ / BK)
#define PLANE  ((size_t)N_BH * L_SEQ * D_HEAD)   // elems per bf16 plane (4,194,304)

typedef float f32x4 __attribute__((ext_vector_type(4)));
typedef short s16x8 __attribute__((ext_vector_type(8)));

#define MFMA16(A,B,C) __builtin_amdgcn_mfma_f32_16x16x32_bf16((A),(B),(C),0,0,0)

__device__ __forceinline__ unsigned int bf16_rne_u(float x) {
    union { float f; unsigned int u; } c; c.f = x;
    return (c.u + 0x7FFFu + ((c.u >> 16) & 1u)) >> 16;
}
__device__ __forceinline__ float bf16_f32(unsigned int h) {
    union { unsigned int u; float f; } c; c.u = h << 16;
    return c.f;
}

// ---------- prep: fp32 -> bf16 hi/lo planes. Q,K row-major [bh][L][64];
// ---------- V transposed [bh][64][L]. One block = one 64-row tile of one bh.
__global__ __launch_bounds__(NT)
void prep_kernel(const float* __restrict__ qg, const float* __restrict__ kg,
                 const float* __restrict__ vg, unsigned short* __restrict__ W)
{
    __shared__ float VT[64][68];
    const int t = threadIdx.x;
    const int tile = blockIdx.x, bh = blockIdx.y;
    const size_t tb = ((size_t)bh * L_SEQ + (size_t)tile * 64) * D_HEAD;

    unsigned short* QH = W;
    unsigned short* QL = W + PLANE;
    unsigned short* KH = W + 2 * PLANE;
    unsigned short* KL = W + 3 * PLANE;
    unsigned short* VTH = W + 4 * PLANE + (size_t)bh * D_HEAD * L_SEQ;
    unsigned short* VTL = W + 5 * PLANE + (size_t)bh * D_HEAD * L_SEQ;

    #pragma unroll
    for (int ii = 0; ii < 4; ++ii) {
        int idx = ii * NT + t;
        int r = idx >> 4, c4 = idx & 15;
        size_t o = tb + (size_t)r * D_HEAD + c4 * 4;
        {   // Q
            float4 val = *(const float4*)(qg + o);
            ushort4 h, l;
            unsigned hx = bf16_rne_u(val.x), hy = bf16_rne_u(val.y);
            unsigned hz = bf16_rne_u(val.z), hw = bf16_rne_u(val.w);
            h.x = (unsigned short)hx; h.y = (unsigned short)hy;
            h.z = (unsigned short)hz; h.w = (unsigned short)hw;
            l.x = (unsigned short)bf16_rne_u(val.x - bf16_f32(hx));
            l.y = (unsigned short)bf16_rne_u(val.y - bf16_f32(hy));
            l.z = (unsigned short)bf16_rne_u(val.z - bf16_f32(hz));
            l.w = (unsigned short)bf16_rne_u(val.w - bf16_f32(hw));
            *(ushort4*)(QH + o) = h;
            *(ushort4*)(QL + o) = l;
        }
        {   // K
            float4 val = *(const float4*)(kg + o);
            ushort4 h, l;
            unsigned hx = bf16_rne_u(val.x), hy = bf16_rne_u(val.y);
            unsigned hz = bf16_rne_u(val.z), hw = bf16_rne_u(val.w);
            h.x = (unsigned short)hx; h.y = (unsigned short)hy;
            h.z = (unsigned short)hz; h.w = (unsigned short)hw;
            l.x = (unsigned short)bf16_rne_u(val.x - bf16_f32(hx));
            l.y = (unsigned short)bf16_rne_u(val.y - bf16_f32(hy));
            l.z = (unsigned short)bf16_rne_u(val.z - bf16_f32(hz));
            l.w = (unsigned short)bf16_rne_u(val.w - bf16_f32(hw));
            *(ushort4*)(KH + o) = h;
            *(ushort4*)(KL + o) = l;
        }
        {   // V -> LDS for transpose
            float4 val = *(const float4*)(vg + o);
            *(float4*)(&VT[r][c4 * 4]) = val;
        }
    }
    __syncthreads();
    #pragma unroll
    for (int ii = 0; ii < 2; ++ii) {
        int item = ii * NT + t;
        int d = item >> 3, jc = item & 7;
        s16x8 hv, lv;
        #pragma unroll
        for (int j = 0; j < 8; ++j) {
            float x = VT[jc * 8 + j][d];
            unsigned h = bf16_rne_u(x);
            hv[j] = (short)h;
            lv[j] = (short)bf16_rne_u(x - bf16_f32(h));
        }
        size_t o = (size_t)d * L_SEQ + (size_t)tile * 64 + jc * 8;
        *(s16x8*)(VTH + o) = hv;
        *(s16x8*)(VTL + o) = lv;
    }
}

// ---------- main ----------
__global__ __launch_bounds__(NT, 3)
void sdpa_main(const unsigned short* __restrict__ W,
               float* __restrict__ ctx, float* __restrict__ attn)
{
    extern __shared__ char lds[];
    char* KHs = lds;               // 8KB, swizzled [64 rows][128B]
    char* KLs = lds + 8192;
    char* VHs = lds + 16384;
    char* VLs = lds + 24576;
    float* PS = (float*)(lds + 32768);   // per-wave [16][68] f32 scratch x4

    const int t = threadIdx.x;
    const int lane = t & 63, wid = t >> 6;
    const int c = lane & 15, g = lane >> 4;

    // XCD-bijective swizzle: 1024 blocks, 8 XCDs -> XCD x owns bh 4x..4x+3
    const int orig = blockIdx.x;
    const int wg = (orig & 7) * 128 + (orig >> 3);
    const int bh = wg >> 5, qb = wg & 31;
    const int q0 = qb * BQ;

    const unsigned short* QH = W;
    const unsigned short* QL = W + PLANE;
    const unsigned short* KHb = W + 2 * PLANE + (size_t)bh * L_SEQ * D_HEAD;
    const unsigned short* KLb = W + 3 * PLANE + (size_t)bh * L_SEQ * D_HEAD;
    const unsigned short* VHb = W + 4 * PLANE + (size_t)bh * D_HEAD * L_SEQ;
    const unsigned short* VLb = W + 5 * PLANE + (size_t)bh * D_HEAD * L_SEQ;

    float* PSw = PS + wid * (16 * 68);

    // Q fragments (hi/lo), row = this wave's 16 rows, k = kf*32 + g*8 + i
    s16x8 qhi[2], qlo[2];
    {
        size_t qo = ((size_t)bh * L_SEQ + q0 + wid * 16 + c) * D_HEAD + g * 8;
        qhi[0] = *(const s16x8*)(QH + qo);
        qhi[1] = *(const s16x8*)(QH + qo + 32);
        qlo[0] = *(const s16x8*)(QL + qo);
        qlo[1] = *(const s16x8*)(QL + qo + 32);
    }

    // staging geometry: 2x 16B chunks per thread per plane
    const int i0 = t, i1 = NT + t;
    const int r0 = i0 >> 3, c0 = i0 & 7;
    const int r1 = i1 >> 3, c1 = i1 & 7;
    const int ld0 = r0 * 128 + ((c0 * 16) ^ ((r0 & 7) << 4));
    const int ld1 = r1 * 128 + ((c1 * 16) ^ ((r1 & 7) << 4));
    const size_t ks0 = (size_t)r0 * D_HEAD + c0 * 8;   // K-plane elem offset in tile
    const size_t ks1 = (size_t)r1 * D_HEAD + c1 * 8;
    const size_t vs0 = (size_t)r0 * L_SEQ + c0 * 8;    // V-plane elem offset (row d=r)
    const size_t vs1 = (size_t)r1 * L_SEQ + c1 * 8;

    // ======== Pass A: rowsums of exp(QK^T/8), hi-plane only ========
    float rs[4] = {0.f, 0.f, 0.f, 0.f};
    uint4 pk0 = *(const uint4*)(KHb + ks0);
    uint4 pk1 = *(const uint4*)(KHb + ks1);

    #pragma unroll 1
    for (int kt = 0; kt < NKT; ++kt) {
        __syncthreads();
        *(uint4*)(KHs + ld0) = pk0;
        *(uint4*)(KHs + ld1) = pk1;
        __syncthreads();
        if (kt + 1 < NKT) {
            const unsigned short* kn = KHb + (size_t)(kt + 1) * BK * D_HEAD;
            pk0 = *(const uint4*)(kn + ks0);
            pk1 = *(const uint4*)(kn + ks1);
        }
        #pragma unroll
        for (int cg = 0; cg < 4; ++cg) {
            int j = cg * 16 + c, key = (j & 7) << 4;
            const char* rh = KHs + j * 128;
            s16x8 b0 = *(const s16x8*)(rh + ((g * 16) ^ key));
            s16x8 b1 = *(const s16x8*)(rh + ((64 + g * 16) ^ key));
            f32x4 s = {0.f, 0.f, 0.f, 0.f};
            s = MFMA16(qhi[0], b0, s);
            s = MFMA16(qhi[1], b1, s);
            #pragma unroll
            for (int r = 0; r < 4; ++r) rs[r] += __expf(s[r] * 0.125f);
        }
    }
    float inv[4];
    #pragma unroll
    for (int r = 0; r < 4; ++r) {
        float s = rs[r];
        s += __shfl_xor(s, 1); s += __shfl_xor(s, 2);
        s += __shfl_xor(s, 4); s += __shfl_xor(s, 8);
        inv[r] = 1.0f / s;
    }

    // ======== Pass B: bf16x3 QK^T -> p -> attn + PV ========
    float* ab = attn + ((size_t)bh * L_SEQ + q0 + wid * 16) * (size_t)L_SEQ;
    f32x4 cacc[4];
    #pragma unroll
    for (int cg = 0; cg < 4; ++cg) cacc[cg] = (f32x4){0.f, 0.f, 0.f, 0.f};

    uint4 kh0 = *(const uint4*)(KHb + ks0), kh1 = *(const uint4*)(KHb + ks1);
    uint4 kl0 = *(const uint4*)(KLb + ks0), kl1 = *(const uint4*)(KLb + ks1);
    uint4 vh0 = *(const uint4*)(VHb + vs0), vh1 = *(const uint4*)(VHb + vs1);
    uint4 vl0 = *(const uint4*)(VLb + vs0), vl1 = *(const uint4*)(VLb + vs1);

    #pragma unroll 1
    for (int kt = 0; kt < NKT; ++kt) {
        __syncthreads();                       // everyone done with prev tile LDS
        *(uint4*)(KHs + ld0) = kh0;  *(uint4*)(KHs + ld1) = kh1;
        *(uint4*)(KLs + ld0) = kl0;  *(uint4*)(KLs + ld1) = kl1;
        *(uint4*)(VHs + ld0) = vh0;  *(uint4*)(VHs + ld1) = vh1;
        *(uint4*)(VLs + ld0) = vl0;  *(uint4*)(VLs + ld1) = vl1;
        __syncthreads();                       // tile staged
        if (kt + 1 < NKT) {                    // T14: prefetch next tile under compute
            const unsigned short* knh = KHb + (size_t)(kt + 1) * BK * D_HEAD;
            const unsigned short* knl = KLb + (size_t)(kt + 1) * BK * D_HEAD;
            kh0 = *(const uint4*)(knh + ks0);  kh1 = *(const uint4*)(knh + ks1);
            kl0 = *(const uint4*)(knl + ks0);  kl1 = *(const uint4*)(knl + ks1);
            const unsigned short* vnh = VHb + (size_t)(kt + 1) * BK;
            const unsigned short* vnl = VLb + (size_t)(kt + 1) * BK;
            vh0 = *(const uint4*)(vnh + vs0);  vh1 = *(const uint4*)(vnh + vs1);
            vl0 = *(const uint4*)(vnl + vs0);  vl1 = *(const uint4*)(vnl + vs1);
        }

        // QK^T bf16x3 -> p = exp(s/8)*inv -> per-wave scratch
        #pragma unroll
        for (int cg = 0; cg < 4; ++cg) {
            int j = cg * 16 + c, key = (j & 7) << 4;
            const char* rh = KHs + j * 128;
            const char* rl = KLs + j * 128;
            s16x8 bh0 = *(const s16x8*)(rh + ((g * 16) ^ key));
            s16x8 bh1 = *(const s16x8*)(rh + ((64 + g * 16) ^ key));
            s16x8 bl0 = *(const s16x8*)(rl + ((g * 16) ^ key));
            s16x8 bl1 = *(const s16x8*)(rl + ((64 + g * 16) ^ key));
            f32x4 s = {0.f, 0.f, 0.f, 0.f};
            s = MFMA16(qhi[0], bh0, s);
            s = MFMA16(qhi[1], bh1, s);
            s = MFMA16(qlo[0], bh0, s);
            s = MFMA16(qlo[1], bh1, s);
            s = MFMA16(qhi[0], bl0, s);
            s = MFMA16(qhi[1], bl1, s);
            #pragma unroll
            for (int r = 0; r < 4; ++r) {
                float p = __expf(s[r] * 0.125f) * inv[r];
                PSw[(g * 4 + r) * 68 + cg * 16 + c] = p;
            }
        }
        // (wave-local PSw: no barrier needed, compiler inserts lgkm waits)

        // attn store: 4 rows x 64B segments per instruction, fp32 exact p
        #pragma unroll
        for (int it = 0; it < 4; ++it) {
            int r2 = it * 4 + g;
            float4 pv = *(const float4*)(PSw + r2 * 68 + c * 4);
            *(float4*)(ab + (size_t)r2 * L_SEQ + kt * BK + c * 4) = pv;
        }

        // P A-frags hi/lo: row = c, k(j) = kf*32 + g*8 + i
        s16x8 ph[2], pl[2];
        {
            const float* pr = PSw + c * 68;
            #pragma unroll
            for (int kf = 0; kf < 2; ++kf) {
                float4 a = *(const float4*)(pr + kf * 32 + g * 8);
                float4 b = *(const float4*)(pr + kf * 32 + g * 8 + 4);
                float vv[8] = {a.x, a.y, a.z, a.w, b.x, b.y, b.z, b.w};
                #pragma unroll
                for (int i = 0; i < 8; ++i) {
                    unsigned h = bf16_rne_u(vv[i]);
                    ph[kf][i] = (short)h;
                    pl[kf][i] = (short)bf16_rne_u(vv[i] - bf16_f32(h));
                }
            }
        }

        // PV bf16x3
        #pragma unroll
        for (int cg = 0; cg < 4; ++cg) {
            int d = cg * 16 + c, key = (d & 7) << 4;
            const char* rh = VHs + d * 128;
            const char* rl = VLs + d * 128;
            s16x8 wh0 = *(const s16x8*)(rh + ((g * 16) ^ key));
            s16x8 wh1 = *(const s16x8*)(rh + ((64 + g * 16) ^ key));
            s16x8 wl0 = *(const s16x8*)(rl + ((g * 16) ^ key));
            s16x8 wl1 = *(const s16x8*)(rl + ((64 + g * 16) ^ key));
            f32x4 cc = cacc[cg];
            cc = MFMA16(ph[0], wh0, cc);
            cc = MFMA16(ph[1], wh1, cc);
            cc = MFMA16(pl[0], wh0, cc);
            cc = MFMA16(pl[1], wh1, cc);
            cc = MFMA16(ph[0], wl0, cc);
            cc = MFMA16(ph[1], wl1, cc);
            cacc[cg] = cc;
        }
    }

    // ctx store: C[row = g*4+r][d = cg*16+c]
    float* cb = ctx + ((size_t)bh * L_SEQ + q0 + wid * 16) * D_HEAD;
    #pragma unroll
    for (int cg = 0; cg < 4; ++cg) {
        #pragma unroll
        for (int r = 0; r < 4; ++r) {
            cb[(size_t)(g * 4 + r) * D_HEAD + cg * 16 + c] = cacc[cg][r];
        }
    }
}

extern "C" void kernel_launch(void* const* d_in, const int* in_sizes, int n_in,
                              void* d_out, int out_size, void* d_ws, size_t ws_size,
                              hipStream_t stream) {
    const float* q = (const float*)d_in[0];
    const float* k = (const float*)d_in[1];
    const float* v = (const float*)d_in[2];
    float* ctx  = (float*)d_out;
    float* attn = ctx + (size_t)N_BH * L_SEQ * D_HEAD;  // context first, then attention
    unsigned short* W = (unsigned short*)d_ws;          // needs 6*PLANE*2B = 50.3 MB

    hipLaunchKernelGGL(prep_kernel, dim3(L_SEQ / 64, N_BH), dim3(NT), 0, stream,
                       q, k, v, W);

    size_t smem = 32768 + (size_t)4 * 16 * 68 * sizeof(float);  // 50176 B
    hipLaunchKernelGGL(sdpa_main, dim3(L_SEQ / BQ * N_BH), dim3(NT), smem, stream,
                       W, ctx, attn);
}